// Round 2
// baseline (230.050 us; speedup 1.0000x reference)
//
#include <hip/hip_runtime.h>

// FocalSelfAttention on MI355X. fp32 I/O, bf16 MFMA compute, fp32 accum.
// B=4, C=128, H=W=48, WS=4 -> 144 windows/batch, 16 q/window, NH=8, hd=16,
// Nkv = 64 local + 720 pooled.
//
// v11 (resubmit; round-1 failure was container acquisition, kernel never ran):
// barrier-free attn main loop. Pooled K/V fragments are gathered DIRECTLY
// from L2 (KVg is 188 KB/batch, shared by 144 blocks -> always L2-resident;
// each wave consumes a disjoint 32B column slice per row, so LDS staging was
// pure overhead: 12 __syncthreads + vmcnt drains + KB bank conflicts).
// Double-buffered register Frag prefetch (tile t+1 loads issued during tile
// t MFMAs) covers L2 latency; waves free-run with ONE barrier total (before
// the out-proj reads At). LDS 52.2 -> 21.8 KB.
// Plus: bijective XCD swizzle (xcd = batch-half) so wc-adjacent windows
// share an XCD -> epilogue 16B-scatter stores and residual F reads merge
// into full 64B lines in L2 (WRITE_SIZE was 24 MB for 4.7 MB of data).

typedef unsigned short u16;
typedef short v8s __attribute__((ext_vector_type(8)));
typedef v8s __attribute__((may_alias)) v8s_am;
typedef short v4s __attribute__((ext_vector_type(4)));
typedef v4s __attribute__((may_alias)) v4s_am;
typedef float v4f __attribute__((ext_vector_type(4)));

#define MFMA_BF16(a, b, c) __builtin_amdgcn_mfma_f32_16x16x32_bf16(a, b, c, 0, 0, 0)

#if __has_builtin(__builtin_amdgcn_mfma_f32_16x16x16bf16_1k)
#define MFMA16(a, b, c) __builtin_amdgcn_mfma_f32_16x16x16bf16_1k(a, b, c, 0, 0, 0)
#else
static __device__ __forceinline__ v4f mfma16_fb(v4s a, v4s b, v4f c) {
    v8s a8 = {a[0], a[1], a[2], a[3], 0, 0, 0, 0};
    v8s b8 = {b[0], b[1], b[2], b[3], 0, 0, 0, 0};
    return MFMA_BF16(a8, b8, c);
}
#define MFMA16(a, b, c) mfma16_fb(a, b, c)
#endif

#if __has_builtin(__builtin_amdgcn_exp2f)
#define EXP2(x) __builtin_amdgcn_exp2f(x)
#else
#define EXP2(x) exp2f(x)
#endif

__device__ __forceinline__ float b2f(u16 u) {
    union { unsigned int i; float f; } x;
    x.i = ((unsigned int)u) << 16;
    return x.f;
}
__device__ __forceinline__ u16 f2b(float f) {
    union { float f; unsigned int i; } x;
    x.f = f;
    unsigned int u = x.i;
    return (u16)((u + 0x7fffu + ((u >> 16) & 1u)) >> 16);
}

// ---------------------------------------------------------------------------
// Kernel 1: blocks 0..287: transpose fp32 NCHW -> bf16 token-major
// Xt[9216][128] (32 px/block) + per-pixel LN stats (mu, rstd) -> MuRs.
// Blocks 288..303: weights fp32->bf16 into Wb; block 288 also ln params.
__global__ __launch_bounds__(256) void k_transpose_prep(
    const float* __restrict__ F,
    const float* __restrict__ qw, const float* __restrict__ kvw,
    const float* __restrict__ ow,
    const float* __restrict__ lnw, const float* __restrict__ lnb,
    u16* __restrict__ Xt, u16* __restrict__ Wb, float* __restrict__ MuRs)
{
    int blk = blockIdx.x;
    int t = threadIdx.x;
    if (blk >= 288) {   // weight conversion: 16 blocks x 256 thr x 16 f32
        int base = (blk - 288) * 4096 + t * 16;
#pragma unroll
        for (int i = 0; i < 4; ++i) {
            int idx = base + i * 4;
            const float* src; int off;
            if (idx < 16384)      { src = qw;  off = idx; }
            else if (idx < 49152) { src = kvw; off = idx - 16384; }
            else                  { src = ow;  off = idx - 49152; }
            float4 v = *(const float4*)(src + off);
            unsigned long long packed =
                (unsigned long long)f2b(v.x) |
                ((unsigned long long)f2b(v.y) << 16) |
                ((unsigned long long)f2b(v.z) << 32) |
                ((unsigned long long)f2b(v.w) << 48);
            *(unsigned long long*)(Wb + idx) = packed;
        }
        if (blk == 288) {   // ln params -> bf16 at Wb+65536
            Wb[65536 + t] = f2b(t < 128 ? lnw[t] : lnb[t - 128]);
        }
        return;
    }
    __shared__ u16 X[128][34];
    int b = blk / 72;
    int p0 = (blk % 72) * 32;
#pragma unroll 4
    for (int i = 0; i < 16; ++i) {
        int c = i * 8 + (t >> 5);
        int pix = t & 31;
        X[c][pix] = f2b(F[((size_t)(b * 128 + c)) * 2304 + p0 + pix]);
    }
    __syncthreads();
    int pix = t >> 3;
    int c0 = (t & 7) * 16;
    size_t row = (size_t)(b * 2304 + p0 + pix) * 128;
    float s = 0.f, s2 = 0.f;
#pragma unroll
    for (int sg = 0; sg < 2; ++sg) {
        v8s raw;
#pragma unroll
        for (int j = 0; j < 8; ++j) {
            u16 u = X[c0 + sg * 8 + j][pix];
            raw[j] = (short)u;
            float v = b2f(u);
            s += v; s2 += v * v;
        }
        *(v8s_am*)&Xt[row + c0 + sg * 8] = raw;
    }
    // 8 consecutive lanes own one pixel
    s += __shfl_xor(s, 1);  s2 += __shfl_xor(s2, 1);
    s += __shfl_xor(s, 2);  s2 += __shfl_xor(s2, 2);
    s += __shfl_xor(s, 4);  s2 += __shfl_xor(s2, 4);
    if ((t & 7) == 0) {
        float mean = s * (1.f / 128.f);
        float var = s2 * (1.f / 128.f) - mean * mean;
        float rstd = rsqrtf(var + 1e-5f);
        MuRs[(b * 2304 + p0 + pix) * 2]     = mean;
        MuRs[(b * 2304 + p0 + pix) * 2 + 1] = rstd;
    }
}

// ---------------------------------------------------------------------------
// Kernel 2: pooled tokens directly from F (fp32 NCHW). 180 blocks x 256.
__global__ __launch_bounds__(256) void k_pool(
    const float* __restrict__ F, u16* __restrict__ Pml)
{
    int gid = blockIdx.x * 256 + threadIdx.x;
    int row = gid >> 4;
    int seg = gid & 15;
    v8s outv;
    if (row < 2304) {        // mid: avg 2x2
        int b = row / 576, r = row % 576;
        int i = r / 24, j = r % 24;
#pragma unroll
        for (int jc = 0; jc < 8; ++jc) {
            int c = seg * 8 + jc;
            const float* src = F + ((size_t)(b * 128 + c)) * 2304 + (2 * i) * 48 + 2 * j;
            float2 a = *(const float2*)src;
            float2 d = *(const float2*)(src + 48);
            outv[jc] = (short)f2b((a.x + a.y + d.x + d.y) * 0.25f);
        }
    } else {                 // glo: avg 4x4
        int r2 = row - 2304;
        int b = r2 / 144, r = r2 % 144;
        int i = r / 12, j = r % 12;
#pragma unroll
        for (int jc = 0; jc < 8; ++jc) {
            int c = seg * 8 + jc;
            const float* src = F + ((size_t)(b * 128 + c)) * 2304 + (4 * i) * 48 + 4 * j;
            float s = 0.f;
#pragma unroll
            for (int di = 0; di < 4; ++di) {
                float4 v = *(const float4*)(src + di * 48);
                s += (v.x + v.y) + (v.z + v.w);
            }
            outv[jc] = (short)f2b(s * 0.0625f);
        }
    }
    *(v8s_am*)&Pml[((size_t)row) * 128 + seg * 8] = outv;
}

// ---------------------------------------------------------------------------
// Kernel 3: mid/glo K/V projection from Pml.
// K -> KVg[2880][128] token-major; V -> VTg[b][128 ch][720 tok] transposed.
__global__ __launch_bounds__(256) void k_gemm_kv(
    const u16* __restrict__ Pml,
    const u16* __restrict__ W,
    const float* __restrict__ bias,
    u16* __restrict__ KVg,
    u16* __restrict__ VTg)
{
    __shared__ u16 Al[64][136];
    __shared__ u16 Wl[64][136];
    int tm = blockIdx.x * 64, tn = blockIdx.y * 64;
    int t = threadIdx.x;
    {
        int seg = t & 15, r0 = t >> 4;
#pragma unroll
        for (int i = 0; i < 4; ++i) {
            int r = r0 + 16 * i;
            *(v8s_am*)&Al[r][seg * 8] = *(const v8s_am*)&Pml[((size_t)(tm + r)) * 128 + seg * 8];
            *(v8s_am*)&Wl[r][seg * 8] = *(const v8s_am*)&W[((size_t)(tn + r)) * 128 + seg * 8];
        }
    }
    __syncthreads();
    int lane = t & 63, wave = t >> 6;
    int n15 = lane & 15, quad = lane >> 4;
    int wm = (wave & 1) * 32, wn = (wave >> 1) * 32;
    v4f acc[2][2] = {};
#pragma unroll
    for (int kc = 0; kc < 4; ++kc) {
        v8s a[2], bb[2];
#pragma unroll
        for (int im = 0; im < 2; ++im)
            a[im] = *(const v8s_am*)&Al[wm + im * 16 + n15][kc * 32 + quad * 8];
#pragma unroll
        for (int in = 0; in < 2; ++in)
            bb[in] = *(const v8s_am*)&Wl[wn + in * 16 + n15][kc * 32 + quad * 8];
#pragma unroll
        for (int im = 0; im < 2; ++im)
#pragma unroll
            for (int in = 0; in < 2; ++in)
                acc[im][in] = MFMA_BF16(a[im], bb[in], acc[im][in]);
    }
#pragma unroll
    for (int in = 0; in < 2; ++in) {
        int n = tn + wn + in * 16 + n15;
        float bv = bias[n];
#pragma unroll
        for (int im = 0; im < 2; ++im) {
            int mbase = tm + wm + im * 16 + quad * 4;
#pragma unroll
            for (int r = 0; r < 4; ++r) {
                int m = mbase + r;
                u16 h = f2b(acc[im][in][r] + bv);
                if (n < 128) {
                    KVg[((size_t)m) * 128 + n] = h;
                } else {
                    int ch = n - 128, bb2, tok;
                    if (m < 2304) { bb2 = m / 576; tok = m % 576; }
                    else { int r2 = m - 2304; bb2 = r2 / 144; tok = 576 + r2 % 144; }
                    VTg[((size_t)(bb2 * 128 + ch)) * 720 + tok] = h;
                }
            }
        }
    }
}

// ---------------------------------------------------------------------------
// Kernel 4 helpers: register-resident pooled K/V tile fragments.
// kb0 = KVg + n15*128 + wave*16 + quad*4     (e adds +64 elements)
// vb0 = VTg + b*92160 + (wave*16+n15)*720 + quad*4  (e adds +46080)
struct Frag { v4s k[2][4]; v4s v[2][4]; };

__device__ __forceinline__ void load_tile(Frag& f, const u16* kb0, const u16* vb0,
                                          int rb128, int t64)
{
#pragma unroll
    for (int e = 0; e < 2; ++e)
#pragma unroll
        for (int g = 0; g < 4; ++g) {
            f.k[e][g] = *(const v4s_am*)(kb0 + e * 64 + rb128 + g * 2048);
            f.v[e][g] = *(const v4s_am*)(vb0 + e * 46080 + t64 + g * 16);
        }
}

__device__ __forceinline__ void load_tile11(Frag& f, const u16* kb0, const u16* vb0,
                                            int b)
{
    int rb128 = 294912 + b * 18432 + 16384;   // glo tokens 128..143
#pragma unroll
    for (int e = 0; e < 2; ++e) {
        f.k[e][0] = *(const v4s_am*)(kb0 + e * 64 + rb128);
        f.v[e][0] = *(const v4s_am*)(vb0 + e * 46080 + 704);
    }
}

__device__ __forceinline__ int rb128f(int b, int t) {
    return (t < 9) ? (b * 73728 + t * 8192) : (294912 + b * 18432 + (t - 9) * 8192);
}

template<int NG>
__device__ __forceinline__ void tile_attn(const Frag& f, const v4s* qf2,
                                          v4f* oacc, float* ls)
{
    v4f zz = {0.f, 0.f, 0.f, 0.f};
#pragma unroll
    for (int g = 0; g < NG; ++g)
#pragma unroll
        for (int e = 0; e < 2; ++e) {
            v4f St = MFMA16(f.k[e][g], qf2[e], zz);
            float p0 = EXP2(St[0]), p1 = EXP2(St[1]);
            float p2 = EXP2(St[2]), p3 = EXP2(St[3]);
            ls[e] += (p0 + p1) + (p2 + p3);
            v4s pk = {(short)f2b(p0), (short)f2b(p1), (short)f2b(p2), (short)f2b(p3)};
            oacc[e] = MFMA16(f.v[e][g], pk, oacc[e]);
        }
}

// ---------------------------------------------------------------------------
// Kernel 4: fused per-window attention. 576 blocks x 256 (4 waves), wave w
// handles heads {w, w+4}. Barrier-free main loop, LDS 21.8 KB, 4 blocks/CU.
__global__ __launch_bounds__(256, 4) void k_attn_fused(
    const float* __restrict__ F,
    const u16* __restrict__ Xt,
    const float* __restrict__ MuRs,
    const u16* __restrict__ KVg,
    const u16* __restrict__ VTg,
    const u16* __restrict__ Wb,     // [qwb|kvwb|owb|lnwb|lnbb]
    const float* __restrict__ qb,
    const float* __restrict__ kvb,
    const float* __restrict__ ob,
    float* __restrict__ Out)
{
    __shared__ u16 VtW[4][32][68];   // per-wave local V^T (wave-private)
    __shared__ u16 At[16][136];      // attended tokens for out-proj

    const u16* qwb  = Wb;
    const u16* kvwb = Wb + 16384;
    const u16* owb  = Wb + 49152;
    const u16* lnwb = Wb + 65536;
    const u16* lnbb = Wb + 65664;

    // Bijective XCD swizzle: xcd = blk%8 -> one batch-half (6 wr-rows x all
    // 12 wc) per XCD. wc-adjacent windows share the XCD's L2 so the 16B
    // NCHW epilogue stores / residual reads merge into full 64B lines, and
    // the per-XCD working set (~1.4 MB: one batch's Xt/F/KVg/VTg slices)
    // stays L2-resident.
    int blk = blockIdx.x;
    int xcd = blk & 7, jj = blk >> 3;       // jj in 0..71
    int b = xcd >> 1;
    int wr = (xcd & 1) * 6 + jj / 12;
    int wc = jj % 12;

    int t = threadIdx.x;
    int lane = t & 63, wave = t >> 6, n15 = lane & 15, quad = lane >> 4;
    v8s zf8 = {};
    v4f zz4 = {0.f, 0.f, 0.f, 0.f};
    const float QSCALE = 0.25f * 1.44269504f;

    // --- per-lane LN'd window token B-fragments (tok = n15) ---
    int qh = wr * 4 + (n15 >> 2), qw_ = wc * 4 + (n15 & 3);
    int qpix = b * 2304 + qh * 48 + qw_;
    float mu = MuRs[qpix * 2], rstd = MuRs[qpix * 2 + 1];
    v8s xln[4];
#pragma unroll
    for (int kc = 0; kc < 4; ++kc) {
        v8s x  = *(const v8s_am*)&Xt[(size_t)qpix * 128 + kc * 32 + quad * 8];
        v8s lw = *(const v8s_am*)&lnwb[kc * 32 + quad * 8];
        v8s lb = *(const v8s_am*)&lnbb[kc * 32 + quad * 8];
        v8s y;
#pragma unroll
        for (int j = 0; j < 8; ++j)
            y[j] = (short)f2b((b2f((u16)x[j]) - mu) * rstd * b2f((u16)lw[j]) + b2f((u16)lb[j]));
        xln[kc] = y;
    }

    // --- Q projection TRANSPOSED: D[och=quad*4+r][q=n15] == QK B-operand ---
    v4s qf2[2];
#pragma unroll
    for (int e = 0; e < 2; ++e) {
        int n0 = wave * 16 + e * 64;
        v4f qacc = zz4;
#pragma unroll
        for (int kc = 0; kc < 4; ++kc) {
            v8s aw = *(const v8s_am*)&qwb[((size_t)(n0 + n15)) * 128 + kc * 32 + quad * 8];
            qacc = MFMA_BF16(aw, xln[kc], qacc);
        }
        v4s q4;
#pragma unroll
        for (int r = 0; r < 4; ++r)
            q4[r] = (short)f2b((qacc[r] + qb[n0 + quad * 4 + r]) * QSCALE);
        qf2[e] = q4;
    }

    // --- local K/V projection TRANSPOSED per wave (its 2 heads only) ---
    v4s kfloc[2][4];
#pragma unroll
    for (int g = 0; g < 4; ++g) {
        int tl = g * 16 + n15;
        int fh = tl >> 3, fw = tl & 7;
        int hh = wr * 4 - 2 + fh, ww = wc * 4 - 2 + fw;
        bool valid = (hh >= 0 && hh < 48 && ww >= 0 && ww < 48);
        size_t arow = (size_t)(b * 2304 + hh * 48 + ww) * 128;
        v8s xb[4];
#pragma unroll
        for (int kc = 0; kc < 4; ++kc) {
            v8s v = zf8;
            if (valid) v = *(const v8s_am*)&Xt[arow + kc * 32 + quad * 8];
            xb[kc] = v;
        }
#pragma unroll
        for (int s = 0; s < 4; ++s) {    // strips: K-e0, K-e1, V-e0, V-e1
            int sbase = (s & 1) * 64 + (s >> 1) * 128 + wave * 16;
            v4f acc = zz4;
#pragma unroll
            for (int kc = 0; kc < 4; ++kc) {
                v8s aw = *(const v8s_am*)&kvwb[((size_t)(sbase + n15)) * 128 + kc * 32 + quad * 8];
                acc = MFMA_BF16(aw, xb[kc], acc);
            }
            if (s < 2) {
                v4s k4;
#pragma unroll
                for (int r = 0; r < 4; ++r)
                    k4[r] = (short)f2b(acc[r] + kvb[sbase + quad * 4 + r]);
                kfloc[s][g] = k4;
            } else {
                int e = s - 2;
#pragma unroll
                for (int r = 0; r < 4; ++r)
                    VtW[wave][e * 16 + quad * 4 + r][g * 16 + n15] =
                        f2b(acc[r] + kvb[sbase + quad * 4 + r]);
            }
        }
    }

    // --- issue tile-0 pooled fragment gathers (cover under local attn) ---
    const u16* kb0 = KVg + (size_t)n15 * 128 + wave * 16 + quad * 4;
    const u16* vb0 = VTg + (size_t)b * 92160 + ((size_t)(wave * 16 + n15)) * 720 + quad * 4;
    Frag fa, fb;
    load_tile(fa, kb0, vb0, b * 73728, 0);

    v4f oacc[2] = {};
    float ls[2] = {0.f, 0.f};

    // --- local chunk (K frags in regs, V from wave-private LDS slice;
    //     VtW[wave] is wave-private -> lgkm wait, no barrier) ---
    asm volatile("s_waitcnt lgkmcnt(0)" ::: "memory");
#pragma unroll
    for (int g = 0; g < 4; ++g) {
#pragma unroll
        for (int e = 0; e < 2; ++e) {
            v4f St = MFMA16(kfloc[e][g], qf2[e], zz4);   // S^T[tok=quad*4+r][q=n15]
            float p0 = EXP2(St[0]), p1 = EXP2(St[1]);
            float p2 = EXP2(St[2]), p3 = EXP2(St[3]);
            ls[e] += (p0 + p1) + (p2 + p3);
            v4s pk = {(short)f2b(p0), (short)f2b(p1), (short)f2b(p2), (short)f2b(p3)};
            v4s vf = *(const v4s_am*)&VtW[wave][e * 16 + n15][g * 16 + quad * 4];
            oacc[e] = MFMA16(vf, pk, oacc[e]);           // O^T[ch=quad*4+r][q=n15]
        }
    }

    // --- pooled tiles 0..11: barrier-free, register double-buffered.
    //     Tile t+1 gathers issued before tile t MFMAs; all reads L2-hot. ---
#pragma unroll
    for (int tt = 0; tt <= 10; tt += 2) {
        if (tt + 1 <= 10) load_tile(fb, kb0, vb0, rb128f(b, tt + 1), (tt + 1) * 64);
        else              load_tile11(fb, kb0, vb0, b);
        tile_attn<4>(fa, qf2, oacc, ls);
        if (tt + 1 <= 10) {
            if (tt + 2 <= 10) load_tile(fa, kb0, vb0, rb128f(b, tt + 2), (tt + 2) * 64);
            else              load_tile11(fa, kb0, vb0, b);
            tile_attn<4>(fb, qf2, oacc, ls);
        }
    }
    tile_attn<1>(fb, qf2, oacc, ls);     // tile 11: 16 toks (glo 128..143)

    // --- l reduce; write attended into At ---
    u16* Atp = &At[0][0];
#pragma unroll
    for (int e = 0; e < 2; ++e) {
        ls[e] += __shfl_xor(ls[e], 16);
        ls[e] += __shfl_xor(ls[e], 32);
        float inv = 1.f / ls[e];
        int head = wave + e * 4;
        v4s a4 = {(short)f2b(oacc[e][0] * inv), (short)f2b(oacc[e][1] * inv),
                  (short)f2b(oacc[e][2] * inv), (short)f2b(oacc[e][3] * inv)};
        *(v4s_am*)&Atp[n15 * 136 + head * 16 + quad * 4] = a4;
    }
    __syncthreads();    // the only block-wide barrier in this kernel

    // --- out projection + bias + fp32 residual, scatter NCHW ---
    {
        int n0 = wave * 32;
        v4f oa[2] = {};
#pragma unroll
        for (int kc = 0; kc < 4; ++kc) {
            v8s af = *(const v8s_am*)&Atp[n15 * 136 + kc * 32 + quad * 8];
#pragma unroll
            for (int in = 0; in < 2; ++in) {
                v8s bf = *(const v8s_am*)&owb[((size_t)(n0 + in * 16 + n15)) * 128 + kc * 32 + quad * 8];
                oa[in] = MFMA_BF16(af, bf, oa[in]);
            }
        }
#pragma unroll
        for (int in = 0; in < 2; ++in) {
            int c = n0 + in * 16 + n15;
            float bv = ob[c];
#pragma unroll
            for (int r = 0; r < 4; ++r) {
                int pix = quad * 4 + r;
                int hh = wr * 4 + (pix >> 2), ww_ = wc * 4 + (pix & 3);
                size_t idx = ((size_t)(b * 128 + c)) * 2304 + hh * 48 + ww_;
                Out[idx] = oa[in][r] + bv + F[idx];
            }
        }
    }
}

// ---------------------------------------------------------------------------
extern "C" void kernel_launch(void* const* d_in, const int* in_sizes, int n_in,
                              void* d_out, int out_size, void* d_ws, size_t ws_size,
                              hipStream_t stream)
{
    const float* F   = (const float*)d_in[0];
    const float* lnw = (const float*)d_in[1];
    const float* lnb = (const float*)d_in[2];
    const float* qw  = (const float*)d_in[3];
    const float* qb  = (const float*)d_in[4];
    const float* kvw = (const float*)d_in[5];
    const float* kvb = (const float*)d_in[6];
    const float* ow  = (const float*)d_in[7];
    const float* ob  = (const float*)d_in[8];
    float* Out = (float*)d_out;

    u16* ws    = (u16*)d_ws;
    u16* Xt    = ws;                    // 9216*128  = 1,179,648 u16
    u16* Pml   = Xt + 9216 * 128;       // 2880*128  =   368,640
    u16* KVg   = Pml + 2880 * 128;      // 2880*128  =   368,640
    u16* VTg   = KVg + 2880 * 128;      // 4*128*720 =   368,640
    u16* Wb    = VTg + 4 * 128 * 720;   // 65,792 [qwb|kvwb|owb|lnwb|lnbb]
    float* MuRs = (float*)(Wb + 65792); // 9216*2 fp32
    // total: ~4.77 MiB
    u16* kvwb = Wb + 16384;

    k_transpose_prep<<<304, 256, 0, stream>>>(F, qw, kvw, ow, lnw, lnb, Xt, Wb, MuRs);
    k_pool<<<180, 256, 0, stream>>>(F, Pml);
    k_gemm_kv<<<dim3(45, 4), 256, 0, stream>>>(Pml, kvwb, kvb, KVg, VTg);
    k_attn_fused<<<576, 256, 0, stream>>>(F, Xt, MuRs, KVg, VTg, Wb,
                                          qb, kvb, ob, Out);
}

// Round 3
// 135.127 us; speedup vs baseline: 1.7025x; 1.7025x over previous
//
#include <hip/hip_runtime.h>

// FocalSelfAttention on MI355X. fp32 I/O, bf16 MFMA compute, fp32 accum.
// B=4, C=128, H=W=48, WS=4 -> 144 windows/batch, 16 q/window, NH=8, hd=16,
// Nkv = 64 local + 720 pooled.
//
// v12: v10 structure (LDS-staged pooled K, 1 barrier/tile) -- v11's register
// double-buffer spilled Frags to scratch (233 MB writes = 576*256*128B*12).
// Changes vs v10:
//  * attn blocks: 512 thr / 8 waves, ONE head per wave (was 4 waves x 2
//    heads). Total waves 2304->4608 (2.25->4.5 per SIMD avg), per-wave
//    serial prologue/exp work halves, per-thread reg state shrinks.
//    LDS unchanged 51 KB -> 3 blocks/CU when VGPR <= 84.
//  * bijective XCD swizzle (xcd = batch-half): wc-adjacent windows share an
//    XCD L2 so the 16B NCHW epilogue stores / residual reads merge lines.
//  * k_pool merged into k_prep (both read F, independent): one less launch.

typedef unsigned short u16;
typedef short v8s __attribute__((ext_vector_type(8)));
typedef v8s __attribute__((may_alias)) v8s_am;
typedef short v4s __attribute__((ext_vector_type(4)));
typedef v4s __attribute__((may_alias)) v4s_am;
typedef float v4f __attribute__((ext_vector_type(4)));

#define MFMA_BF16(a, b, c) __builtin_amdgcn_mfma_f32_16x16x32_bf16(a, b, c, 0, 0, 0)

#if __has_builtin(__builtin_amdgcn_mfma_f32_16x16x16bf16_1k)
#define MFMA16(a, b, c) __builtin_amdgcn_mfma_f32_16x16x16bf16_1k(a, b, c, 0, 0, 0)
#else
static __device__ __forceinline__ v4f mfma16_fb(v4s a, v4s b, v4f c) {
    v8s a8 = {a[0], a[1], a[2], a[3], 0, 0, 0, 0};
    v8s b8 = {b[0], b[1], b[2], b[3], 0, 0, 0, 0};
    return MFMA_BF16(a8, b8, c);
}
#define MFMA16(a, b, c) mfma16_fb(a, b, c)
#endif

#if __has_builtin(__builtin_amdgcn_exp2f)
#define EXP2(x) __builtin_amdgcn_exp2f(x)
#else
#define EXP2(x) exp2f(x)
#endif

__device__ __forceinline__ float b2f(u16 u) {
    union { unsigned int i; float f; } x;
    x.i = ((unsigned int)u) << 16;
    return x.f;
}
__device__ __forceinline__ u16 f2b(float f) {
    union { float f; unsigned int i; } x;
    x.f = f;
    unsigned int u = x.i;
    return (u16)((u + 0x7fffu + ((u >> 16) & 1u)) >> 16);
}

// ---------------------------------------------------------------------------
// Kernel 1 (merged): blocks 0..287 transpose F->Xt + LN stats; 288..303
// weights fp32->bf16; 304..483 pooled tokens (k_pool body, independent of
// the rest -- merging saves one launch).
__global__ __launch_bounds__(256) void k_prep(
    const float* __restrict__ F,
    const float* __restrict__ qw, const float* __restrict__ kvw,
    const float* __restrict__ ow,
    const float* __restrict__ lnw, const float* __restrict__ lnb,
    u16* __restrict__ Xt, u16* __restrict__ Wb, float* __restrict__ MuRs,
    u16* __restrict__ Pml)
{
    int blk = blockIdx.x;
    int t = threadIdx.x;
    if (blk >= 304) {   // ---- pool part: 180 blocks ----
        int gid = (blk - 304) * 256 + t;
        int row = gid >> 4;
        int seg = gid & 15;
        v8s outv;
        if (row < 2304) {        // mid: avg 2x2
            int b = row / 576, r = row % 576;
            int i = r / 24, j = r % 24;
#pragma unroll
            for (int jc = 0; jc < 8; ++jc) {
                int c = seg * 8 + jc;
                const float* src = F + ((size_t)(b * 128 + c)) * 2304 + (2 * i) * 48 + 2 * j;
                float2 a = *(const float2*)src;
                float2 d = *(const float2*)(src + 48);
                outv[jc] = (short)f2b((a.x + a.y + d.x + d.y) * 0.25f);
            }
        } else {                 // glo: avg 4x4
            int r2 = row - 2304;
            int b = r2 / 144, r = r2 % 144;
            int i = r / 12, j = r % 12;
#pragma unroll
            for (int jc = 0; jc < 8; ++jc) {
                int c = seg * 8 + jc;
                const float* src = F + ((size_t)(b * 128 + c)) * 2304 + (4 * i) * 48 + 4 * j;
                float s = 0.f;
#pragma unroll
                for (int di = 0; di < 4; ++di) {
                    float4 v = *(const float4*)(src + di * 48);
                    s += (v.x + v.y) + (v.z + v.w);
                }
                outv[jc] = (short)f2b(s * 0.0625f);
            }
        }
        *(v8s_am*)&Pml[((size_t)row) * 128 + seg * 8] = outv;
        return;
    }
    if (blk >= 288) {   // ---- weight conversion: 16 blocks ----
        int base = (blk - 288) * 4096 + t * 16;
#pragma unroll
        for (int i = 0; i < 4; ++i) {
            int idx = base + i * 4;
            const float* src; int off;
            if (idx < 16384)      { src = qw;  off = idx; }
            else if (idx < 49152) { src = kvw; off = idx - 16384; }
            else                  { src = ow;  off = idx - 49152; }
            float4 v = *(const float4*)(src + off);
            unsigned long long packed =
                (unsigned long long)f2b(v.x) |
                ((unsigned long long)f2b(v.y) << 16) |
                ((unsigned long long)f2b(v.z) << 32) |
                ((unsigned long long)f2b(v.w) << 48);
            *(unsigned long long*)(Wb + idx) = packed;
        }
        if (blk == 288) {
            Wb[65536 + t] = f2b(t < 128 ? lnw[t] : lnb[t - 128]);
        }
        return;
    }
    // ---- transpose + LN stats: 288 blocks ----
    __shared__ u16 X[128][34];
    int b = blk / 72;
    int p0 = (blk % 72) * 32;
#pragma unroll 4
    for (int i = 0; i < 16; ++i) {
        int c = i * 8 + (t >> 5);
        int pix = t & 31;
        X[c][pix] = f2b(F[((size_t)(b * 128 + c)) * 2304 + p0 + pix]);
    }
    __syncthreads();
    int pix = t >> 3;
    int c0 = (t & 7) * 16;
    size_t row = (size_t)(b * 2304 + p0 + pix) * 128;
    float s = 0.f, s2 = 0.f;
#pragma unroll
    for (int sg = 0; sg < 2; ++sg) {
        v8s raw;
#pragma unroll
        for (int j = 0; j < 8; ++j) {
            u16 u = X[c0 + sg * 8 + j][pix];
            raw[j] = (short)u;
            float v = b2f(u);
            s += v; s2 += v * v;
        }
        *(v8s_am*)&Xt[row + c0 + sg * 8] = raw;
    }
    s += __shfl_xor(s, 1);  s2 += __shfl_xor(s2, 1);
    s += __shfl_xor(s, 2);  s2 += __shfl_xor(s2, 2);
    s += __shfl_xor(s, 4);  s2 += __shfl_xor(s2, 4);
    if ((t & 7) == 0) {
        float mean = s * (1.f / 128.f);
        float var = s2 * (1.f / 128.f) - mean * mean;
        float rstd = rsqrtf(var + 1e-5f);
        MuRs[(b * 2304 + p0 + pix) * 2]     = mean;
        MuRs[(b * 2304 + p0 + pix) * 2 + 1] = rstd;
    }
}

// ---------------------------------------------------------------------------
// Kernel 2: mid/glo K/V projection from Pml.
// K -> KVg[2880][128] token-major; V -> VTg[b][128 ch][720 tok] transposed.
__global__ __launch_bounds__(256) void k_gemm_kv(
    const u16* __restrict__ Pml,
    const u16* __restrict__ W,
    const float* __restrict__ bias,
    u16* __restrict__ KVg,
    u16* __restrict__ VTg)
{
    __shared__ u16 Al[64][136];
    __shared__ u16 Wl[64][136];
    int tm = blockIdx.x * 64, tn = blockIdx.y * 64;
    int t = threadIdx.x;
    {
        int seg = t & 15, r0 = t >> 4;
#pragma unroll
        for (int i = 0; i < 4; ++i) {
            int r = r0 + 16 * i;
            *(v8s_am*)&Al[r][seg * 8] = *(const v8s_am*)&Pml[((size_t)(tm + r)) * 128 + seg * 8];
            *(v8s_am*)&Wl[r][seg * 8] = *(const v8s_am*)&W[((size_t)(tn + r)) * 128 + seg * 8];
        }
    }
    __syncthreads();
    int lane = t & 63, wave = t >> 6;
    int n15 = lane & 15, quad = lane >> 4;
    int wm = (wave & 1) * 32, wn = (wave >> 1) * 32;
    v4f acc[2][2] = {};
#pragma unroll
    for (int kc = 0; kc < 4; ++kc) {
        v8s a[2], bb[2];
#pragma unroll
        for (int im = 0; im < 2; ++im)
            a[im] = *(const v8s_am*)&Al[wm + im * 16 + n15][kc * 32 + quad * 8];
#pragma unroll
        for (int in = 0; in < 2; ++in)
            bb[in] = *(const v8s_am*)&Wl[wn + in * 16 + n15][kc * 32 + quad * 8];
#pragma unroll
        for (int im = 0; im < 2; ++im)
#pragma unroll
            for (int in = 0; in < 2; ++in)
                acc[im][in] = MFMA_BF16(a[im], bb[in], acc[im][in]);
    }
#pragma unroll
    for (int in = 0; in < 2; ++in) {
        int n = tn + wn + in * 16 + n15;
        float bv = bias[n];
#pragma unroll
        for (int im = 0; im < 2; ++im) {
            int mbase = tm + wm + im * 16 + quad * 4;
#pragma unroll
            for (int r = 0; r < 4; ++r) {
                int m = mbase + r;
                u16 h = f2b(acc[im][in][r] + bv);
                if (n < 128) {
                    KVg[((size_t)m) * 128 + n] = h;
                } else {
                    int ch = n - 128, bb2, tok;
                    if (m < 2304) { bb2 = m / 576; tok = m % 576; }
                    else { int r2 = m - 2304; bb2 = r2 / 144; tok = 576 + r2 % 144; }
                    VTg[((size_t)(bb2 * 128 + ch)) * 720 + tok] = h;
                }
            }
        }
    }
}

// ---------------------------------------------------------------------------
// Kernel 3: fused per-window attention. 576 blocks x 512 thr (8 waves),
// wave w handles head w only. LDS 51 KB (KB 34.8 + VtW 17.4) -> 3 blocks/CU
// when VGPR <= 84. One barrier per pooled tile (12) + 1 before out-proj.
__global__ __launch_bounds__(512, 4) void k_attn_fused(
    const float* __restrict__ F,
    const u16* __restrict__ Xt,
    const float* __restrict__ MuRs,
    const u16* __restrict__ KVg,
    const u16* __restrict__ VTg,
    const u16* __restrict__ Wb,     // [qwb|kvwb|owb|lnwb|lnbb]
    const float* __restrict__ qb,
    const float* __restrict__ kvb,
    const float* __restrict__ ob,
    float* __restrict__ Out)
{
    __shared__ u16 KB[2][64][136];   // pooled K tiles, double-buffered
    __shared__ u16 VtW[8][16][68];   // per-wave local V^T; At overlays later

    const u16* qwb  = Wb;
    const u16* kvwb = Wb + 16384;
    const u16* owb  = Wb + 49152;
    const u16* lnwb = Wb + 65536;
    const u16* lnbb = Wb + 65664;
    u16* Atp = &VtW[0][0][0];        // [16][136] overlay (4.4 KB of 17.4)

    // Bijective XCD swizzle: xcd = blk&7 -> one batch-half per XCD.
    int blk = blockIdx.x;
    int xcd = blk & 7, jj = blk >> 3;       // jj in 0..71
    int b = xcd >> 1;
    int wr = (xcd & 1) * 6 + jj / 12;
    int wc = jj % 12;

    int t = threadIdx.x;
    int lane = t & 63, wave = t >> 6, n15 = lane & 15, quad = lane >> 4;
    v8s zf8 = {};
    v4f zz4 = {0.f, 0.f, 0.f, 0.f};
    const float QSCALE = 0.25f * 1.44269504f;

    // --- per-lane LN'd window token B-fragments (tok = n15) ---
    int qh = wr * 4 + (n15 >> 2), qw_ = wc * 4 + (n15 & 3);
    int qpix = b * 2304 + qh * 48 + qw_;
    float mu = MuRs[qpix * 2], rstd = MuRs[qpix * 2 + 1];
    v8s xln[4];
#pragma unroll
    for (int kc = 0; kc < 4; ++kc) {
        v8s x  = *(const v8s_am*)&Xt[(size_t)qpix * 128 + kc * 32 + quad * 8];
        v8s lw = *(const v8s_am*)&lnwb[kc * 32 + quad * 8];
        v8s lb = *(const v8s_am*)&lnbb[kc * 32 + quad * 8];
        v8s y;
#pragma unroll
        for (int j = 0; j < 8; ++j)
            y[j] = (short)f2b((b2f((u16)x[j]) - mu) * rstd * b2f((u16)lw[j]) + b2f((u16)lb[j]));
        xln[kc] = y;
    }

    // --- Q projection TRANSPOSED for head=wave: D[d=quad*4+r][q=n15] ---
    v4s qf;
    {
        int n0 = wave * 16;
        v4f qacc = zz4;
#pragma unroll
        for (int kc = 0; kc < 4; ++kc) {
            v8s aw = *(const v8s_am*)&qwb[((size_t)(n0 + n15)) * 128 + kc * 32 + quad * 8];
            qacc = MFMA_BF16(aw, xln[kc], qacc);
        }
#pragma unroll
        for (int r = 0; r < 4; ++r)
            qf[r] = (short)f2b((qacc[r] + qb[n0 + quad * 4 + r]) * QSCALE);
    }

    // --- local K/V projection TRANSPOSED (this wave's head only) ---
    v4s kfloc[4];
#pragma unroll
    for (int g = 0; g < 4; ++g) {
        int tl = g * 16 + n15;
        int fh = tl >> 3, fw = tl & 7;
        int hh = wr * 4 - 2 + fh, ww = wc * 4 - 2 + fw;
        bool valid = (hh >= 0 && hh < 48 && ww >= 0 && ww < 48);
        size_t arow = (size_t)(b * 2304 + hh * 48 + ww) * 128;
        v8s xb[4];
#pragma unroll
        for (int kc = 0; kc < 4; ++kc) {
            v8s v = zf8;
            if (valid) v = *(const v8s_am*)&Xt[arow + kc * 32 + quad * 8];
            xb[kc] = v;
        }
#pragma unroll
        for (int s = 0; s < 2; ++s) {    // s=0: K strip, s=1: V strip
            int sbase = s * 128 + wave * 16;
            v4f acc = zz4;
#pragma unroll
            for (int kc = 0; kc < 4; ++kc) {
                v8s aw = *(const v8s_am*)&kvwb[((size_t)(sbase + n15)) * 128 + kc * 32 + quad * 8];
                acc = MFMA_BF16(aw, xb[kc], acc);
            }
            if (s == 0) {
                v4s k4;
#pragma unroll
                for (int r = 0; r < 4; ++r)
                    k4[r] = (short)f2b(acc[r] + kvb[sbase + quad * 4 + r]);
                kfloc[g] = k4;
            } else {
#pragma unroll
                for (int r = 0; r < 4; ++r)
                    VtW[wave][quad * 4 + r][g * 16 + n15] =
                        f2b(acc[r] + kvb[sbase + quad * 4 + r]);
            }
        }
    }

    // --- issue tile-0 pooled-K staging loads (cover under local attn) ---
    v8s stg[2];
#pragma unroll
    for (int i = 0; i < 2; ++i) {
        int chunk = i * 512 + t;
        stg[i] = *(const v8s_am*)&KVg[((size_t)(b * 576 + (chunk >> 4))) * 128 + (chunk & 15) * 8];
    }

    v4f oacc = zz4;
    float ls = 0.f;
    const u16* VTb = VTg + (size_t)b * 92160;

    // --- local chunk (K frags in regs, V from wave-private LDS slice) ---
    asm volatile("s_waitcnt lgkmcnt(0)" ::: "memory");
#pragma unroll
    for (int g = 0; g < 4; ++g) {
        v4f St = MFMA16(kfloc[g], qf, zz4);     // S^T[tok=quad*4+r][q=n15]
        float p0 = EXP2(St[0]), p1 = EXP2(St[1]);
        float p2 = EXP2(St[2]), p3 = EXP2(St[3]);
        ls += (p0 + p1) + (p2 + p3);
        v4s pk = {(short)f2b(p0), (short)f2b(p1), (short)f2b(p2), (short)f2b(p3)};
        v4s vf = *(const v4s_am*)&VtW[wave][n15][g * 16 + quad * 4];
        oacc = MFMA16(vf, pk, oacc);            // O^T[ch=quad*4+r][q=n15]
    }

    // --- write tile 0 into KB[1] ---
#pragma unroll
    for (int i = 0; i < 2; ++i) {
        int chunk = i * 512 + t;
        *(v8s_am*)&KB[1][chunk >> 4][(chunk & 15) * 8] = stg[i];
    }
    __syncthreads();

    // --- pooled tiles 0..10; tile tb lives in KB[1-(tb&1)] ---
    for (int tb = 0; tb <= 10; ++tb) {
        v4s vp[4];
        {
            const u16* vrow = VTb + (size_t)(wave * 16 + n15) * 720 + tb * 64 + quad * 4;
#pragma unroll
            for (int g = 0; g < 4; ++g)
                vp[g] = *(const v4s_am*)(vrow + g * 16);
        }
        int nt_ = tb + 1;
        int rowbase = (nt_ < 9) ? (b * 576 + nt_ * 64)
                                : (2304 + b * 144 + nt_ * 64 - 576);
        int nrows = (nt_ == 11) ? 16 : 64;
        bool sv[2];
#pragma unroll
        for (int i = 0; i < 2; ++i) {
            int chunk = i * 512 + t;
            int rr = chunk >> 4;
            sv[i] = rr < nrows;
            if (sv[i])
                stg[i] = *(const v8s_am*)&KVg[((size_t)(rowbase + rr)) * 128 + (chunk & 15) * 8];
        }
        const u16 (*KBc)[136] = KB[1 - (tb & 1)];
#pragma unroll
        for (int g = 0; g < 4; ++g) {
            v4s kf = *(const v4s_am*)&KBc[g * 16 + n15][wave * 16 + quad * 4];
            v4f St = MFMA16(kf, qf, zz4);
            float p0 = EXP2(St[0]), p1 = EXP2(St[1]);
            float p2 = EXP2(St[2]), p3 = EXP2(St[3]);
            ls += (p0 + p1) + (p2 + p3);
            v4s pk = {(short)f2b(p0), (short)f2b(p1), (short)f2b(p2), (short)f2b(p3)};
            oacc = MFMA16(vp[g], pk, oacc);
        }
#pragma unroll
        for (int i = 0; i < 2; ++i) {
            if (sv[i]) {
                int chunk = i * 512 + t;
                *(v8s_am*)&KB[tb & 1][chunk >> 4][(chunk & 15) * 8] = stg[i];
            }
        }
        __syncthreads();
    }
    // --- tile 11: 16 toks (glo 128..143), buffer KB[0] ---
    {
        v4s vf = *(const v4s_am*)(VTb + (size_t)(wave * 16 + n15) * 720 + 704 + quad * 4);
        v4s kf = *(const v4s_am*)&KB[0][n15][wave * 16 + quad * 4];
        v4f St = MFMA16(kf, qf, zz4);
        float p0 = EXP2(St[0]), p1 = EXP2(St[1]);
        float p2 = EXP2(St[2]), p3 = EXP2(St[3]);
        ls += (p0 + p1) + (p2 + p3);
        v4s pk = {(short)f2b(p0), (short)f2b(p1), (short)f2b(p2), (short)f2b(p3)};
        oacc = MFMA16(vf, pk, oacc);
    }

    // --- l reduce (across quads of this wave); write attended into At
    //     (overlay on VtW; all VtW reads happened before barrier 1) ---
    ls += __shfl_xor(ls, 16);
    ls += __shfl_xor(ls, 32);
    {
        float inv = 1.f / ls;
        v4s a4 = {(short)f2b(oacc[0] * inv), (short)f2b(oacc[1] * inv),
                  (short)f2b(oacc[2] * inv), (short)f2b(oacc[3] * inv)};
        *(v4s_am*)&Atp[n15 * 136 + wave * 16 + quad * 4] = a4;
    }
    __syncthreads();

    // --- out projection (16 out-ch per wave) + bias + residual, NCHW ---
    {
        int n0 = wave * 16;
        v4f oa = zz4;
#pragma unroll
        for (int kc = 0; kc < 4; ++kc) {
            v8s af = *(const v8s_am*)&Atp[n15 * 136 + kc * 32 + quad * 8];
            v8s bf = *(const v8s_am*)&owb[((size_t)(n0 + n15)) * 128 + kc * 32 + quad * 8];
            oa = MFMA_BF16(af, bf, oa);
        }
        int c = n0 + n15;
        float bv = ob[c];
#pragma unroll
        for (int r = 0; r < 4; ++r) {
            int pix = quad * 4 + r;
            int hh = wr * 4 + (pix >> 2), ww_ = wc * 4 + (pix & 3);
            size_t idx = ((size_t)(b * 128 + c)) * 2304 + hh * 48 + ww_;
            Out[idx] = oa[r] + bv + F[idx];
        }
    }
}

// ---------------------------------------------------------------------------
extern "C" void kernel_launch(void* const* d_in, const int* in_sizes, int n_in,
                              void* d_out, int out_size, void* d_ws, size_t ws_size,
                              hipStream_t stream)
{
    const float* F   = (const float*)d_in[0];
    const float* lnw = (const float*)d_in[1];
    const float* lnb = (const float*)d_in[2];
    const float* qw  = (const float*)d_in[3];
    const float* qb  = (const float*)d_in[4];
    const float* kvw = (const float*)d_in[5];
    const float* kvb = (const float*)d_in[6];
    const float* ow  = (const float*)d_in[7];
    const float* ob  = (const float*)d_in[8];
    float* Out = (float*)d_out;

    u16* ws    = (u16*)d_ws;
    u16* Xt    = ws;                    // 9216*128  = 1,179,648 u16
    u16* Pml   = Xt + 9216 * 128;       // 2880*128  =   368,640
    u16* KVg   = Pml + 2880 * 128;      // 2880*128  =   368,640
    u16* VTg   = KVg + 2880 * 128;      // 4*128*720 =   368,640
    u16* Wb    = VTg + 4 * 128 * 720;   // 65,792 [qwb|kvwb|owb|lnwb|lnbb]
    float* MuRs = (float*)(Wb + 65792); // 9216*2 fp32
    // total: ~4.77 MiB
    u16* kvwb = Wb + 16384;

    k_prep<<<484, 256, 0, stream>>>(F, qw, kvw, ow, lnw, lnb, Xt, Wb, MuRs, Pml);
    k_gemm_kv<<<dim3(45, 4), 256, 0, stream>>>(Pml, kvwb, kvb, KVg, VTg);
    k_attn_fused<<<576, 512, 0, stream>>>(F, Xt, MuRs, KVg, VTg, Wb,
                                          qb, kvb, ob, Out);
}